// Round 8
// baseline (267.368 us; speedup 1.0000x reference)
//
#include <hip/hip_runtime.h>

typedef __attribute__((ext_vector_type(8))) short short8;   // 8 x bf16 (4 VGPR)
typedef __attribute__((ext_vector_type(4))) float f32x4;
typedef __attribute__((ext_vector_type(4))) unsigned uint4v;

#define Bsz 4
#define Cin 256
#define Cout 256
#define Hh 64
#define Ww 64
#define HW 4096
#define NG 16
#define EPSV 1e-5f
#define N16K 16384

#define BSTR 68   // GEMM B-tile row stride in ushorts: 64 data + 4 pad (136 B)

static __device__ __forceinline__ unsigned f2bf(float f) {
    unsigned u = __float_as_uint(f);
    return (u + 0x7fffu + ((u >> 16) & 1u)) >> 16;   // RNE bf16
}

// ---------------------------------------------------------------------------
// Kernel 0 (prep): blocks 0..1023: transpose in [b][c][y][x] -> in_t [b][y][x][c]
//                  blocks 1024..3327: weight reorder -> bf16 wtb[ks][o][32],
//                  ks = (kk*256+c)/32;  + zero GN stats.
// ---------------------------------------------------------------------------
__global__ void prep_kernel(const float* __restrict__ in, float* __restrict__ in_t,
                            const float* __restrict__ w, ushort* __restrict__ wtb,
                            float* __restrict__ stats) {
    const int t = threadIdx.x;
    if (blockIdx.x < 1024) {
        __shared__ float tile[64 * 68];
        const int bx = blockIdx.x;             // b*256 + y*4 + ct
        const int b  = bx >> 8;
        const int y  = (bx >> 2) & 63;
        const int c0 = (bx & 3) * 64;
        const int xr = (t & 15) * 4, cr = t >> 4;
#pragma unroll
        for (int j = 0; j < 4; j++) {
            const int c = cr + j * 16;
            const float4 v = *(const float4*)(in + ((size_t)(b * 256 + c0 + c)) * HW + y * 64 + xr);
            *(float4*)&tile[c * 68 + xr] = v;
        }
        __syncthreads();
        const int cw = (t & 15) * 4, xw = t >> 4;
#pragma unroll
        for (int j = 0; j < 4; j++) {
            const int x = xw + j * 16;
            float4 v;
            v.x = tile[(cw + 0) * 68 + x];
            v.y = tile[(cw + 1) * 68 + x];
            v.z = tile[(cw + 2) * 68 + x];
            v.w = tile[(cw + 3) * 68 + x];
            *(float4*)(in_t + ((size_t)b * HW + y * 64 + x) * 256 + c0 + cw) = v;
        }
    } else {
        if (blockIdx.x == 1024 && t < 128) stats[t] = 0.f;
        const int i = (blockIdx.x - 1024) * 256 + t;    // over 589824
        if (i >= Cout * Cin * 9) return;
        const int o = i / (Cin * 9);
        const int rem = i % (Cin * 9);
        const int c = rem / 9, kk = rem % 9;
        const int ks = kk * 8 + (c >> 5);               // = (kk*256+c)>>5
        wtb[(ks * 256 + o) * 32 + (c & 31)] = (ushort)f2bf(w[i]);
    }
}

// ---------------------------------------------------------------------------
// Kernel 1: im2col — materialize bf16 col[ks2][n][64],  ks2 = (kk*256+c)/64.
// Block = 32 pixels x 256 thr (px 0..31, ce 0..7 -> 32-channel range).
// No inner barriers: pure streaming gather -> pack -> coalesced store.
// ---------------------------------------------------------------------------
__launch_bounds__(256, 4)
__global__ void im2col_kernel(const float* __restrict__ in_t,
                              const float* __restrict__ offs,
                              const float* __restrict__ mask,
                              ushort* __restrict__ col) {
    __shared__ int2  s_ta[9 * 32];
    __shared__ f32x4 s_tw[9 * 32];

    const int t   = threadIdx.x;
    const int px0 = blockIdx.x * 32;          // 512 blocks
    const int b   = px0 >> 12;
    const int h   = (px0 >> 6) & 63;
    const int w0  = px0 & 63;                 // 0 or 32

    // ---- tap precompute: 9 kernel points x 32 pixels ----
    for (int j = t; j < 288; j += 256) {
        const int k = j >> 5, p = j & 31;
        const int wq = w0 + p;
        const float* ob = offs + (size_t)b * 18 * HW + h * Ww + wq;
        const float dy = ob[(2 * k) * HW];
        const float dx = ob[(2 * k + 1) * HW];
        const float m  = mask[((size_t)b * 9 + k) * HW + h * Ww + wq];
        const float y = (float)h + (float)(k / 3 - 1) + dy;
        const float x = (float)wq + (float)(k % 3 - 1) + dx;
        const float y0f = floorf(y), x0f = floorf(x);
        const float ly = y - y0f, lx = x - x0f;
        const float hy = 1.f - ly, hx = 1.f - lx;
        const int y0 = (int)y0f, x0 = (int)x0f;
        const int yc0 = min(max(y0, 0), 63);
        const int yc1 = min(max(y0 + 1, 0), 63);
        const int xb  = min(max(x0, 0), 62);
        float ax = 0.f, ay = 0.f;
        if (x0 == xb) {                       // x0 in [0,62]
            ax = hx; ay = lx;
        } else if (x0 < xb) {                 // x0 < 0
            ax = (x0 + 1 == 0) ? lx : 0.f;
        } else {                              // x0 > 62
            ay = (x0 == 63) ? hx : 0.f;       // x0>=64: both corners OOB
        }
        const float ww0 = (y0 >= 0 && y0 < 64) ? m * hy : 0.f;
        const float ww1 = (y0 + 1 >= 0 && y0 + 1 < 64) ? m * ly : 0.f;
        s_ta[j] = make_int2(yc0 * 64 + xb, yc1 * 64 + xb);
        s_tw[j] = (f32x4){ww0 * ax, ww0 * ay, ww1 * ax, ww1 * ay};
    }
    __syncthreads();

    const int px = t >> 3, ce = t & 7;        // thread: pixel px, channels ce*32..+31
    const int n  = px0 + px;
    const float* base = in_t + ((size_t)b * HW) * 256 + ce * 32;
    ushort* cwn = col + (size_t)n * 64 + (ce & 1) * 32 + ((size_t)(ce >> 1) << 20);

#pragma unroll 1
    for (int kk = 0; kk < 9; kk++) {
        const int2  ad = s_ta[kk * 32 + px];
        const f32x4 tw = s_tw[kk * 32 + px];
        const float* p0 = base + (size_t)ad.x * 256;
        const float* p1 = base + (size_t)ad.y * 256;
        ushort* cw2 = cwn + ((size_t)(kk * 4) << 20);   // plane stride 16384*64
#pragma unroll
        for (int j2 = 0; j2 < 4; j2++) {
            const int o8 = j2 * 8;
            const f32x4 c00 = *(const f32x4*)(p0 + o8);
            const f32x4 c01 = *(const f32x4*)(p0 + o8 + 4);
            const f32x4 c10 = *(const f32x4*)(p0 + 256 + o8);
            const f32x4 c11 = *(const f32x4*)(p0 + 256 + o8 + 4);
            const f32x4 c20 = *(const f32x4*)(p1 + o8);
            const f32x4 c21 = *(const f32x4*)(p1 + o8 + 4);
            const f32x4 c30 = *(const f32x4*)(p1 + 256 + o8);
            const f32x4 c31 = *(const f32x4*)(p1 + 256 + o8 + 4);
            const f32x4 v0 = tw[0] * c00 + tw[1] * c10 + tw[2] * c20 + tw[3] * c30;
            const f32x4 v1 = tw[0] * c01 + tw[1] * c11 + tw[2] * c21 + tw[3] * c31;
            uint4v pk;
            pk[0] = f2bf(v0[0]) | (f2bf(v0[1]) << 16);
            pk[1] = f2bf(v0[2]) | (f2bf(v0[3]) << 16);
            pk[2] = f2bf(v1[0]) | (f2bf(v1[1]) << 16);
            pk[3] = f2bf(v1[2]) | (f2bf(v1[3]) << 16);
            *(uint4v*)(cw2 + o8) = pk;
        }
    }
}

// ---------------------------------------------------------------------------
// Kernel 2: GEMM  out[o][n] = wtb[.][o][.] x col  + bias, + GN partial stats.
// Block: 512 thr (8 waves) = 64 px x M=256. Grid 256. BK=64, dbuf LDS B-tile,
// one barrier/step, 1 coalesced float4-equivalent stage load/thread/step.
// ---------------------------------------------------------------------------
__launch_bounds__(512, 2)
__global__ void gemm_kernel(const ushort* __restrict__ col,
                            const ushort* __restrict__ wtb,
                            const float* __restrict__ bias,
                            float* __restrict__ out,
                            float* __restrict__ stats) {
    __shared__ ushort sB[2][64 * BSTR];       // 2 x 8.5 KB

    const int t  = threadIdx.x;
    const int bx = blockIdx.x;                // 256: b*64 + h
    const int b  = bx >> 6, h = bx & 63;
    const int n0 = bx * 64;
    const int lane = t & 63;
    const int wv   = t >> 6;                  // wave 0..7, m-strip 32*wv
    const int quad = lane >> 4;
    const int l15  = lane & 15;
    const int spx  = t >> 3, part = t & 7;    // staging role: 16B per thread

    f32x4 acc[2][4];
#pragma unroll
    for (int i = 0; i < 2; i++)
#pragma unroll
        for (int nt = 0; nt < 4; nt++) acc[i][nt] = (f32x4){0.f, 0.f, 0.f, 0.f};

    const ushort* stage_src = col + (size_t)n0 * 64 + t * 8;   // +s*N16K*64 per step
    const ushort* wpbase = wtb + ((size_t)(wv * 32 + l15)) * 32 + quad * 8;
    // ks stride in wtb = 256*32 ushorts

    // ---- prologue: stage step 0, prefetch A(step 0) ----
    short8 vst = *(const short8*)stage_src;
    short8 a0c[2], a1c[2], a0n[2], a1n[2];
#pragma unroll
    for (int kh = 0; kh < 2; kh++) {
        a0c[kh] = *(const short8*)(wpbase + (size_t)kh * 8192);
        a1c[kh] = *(const short8*)(wpbase + (size_t)kh * 8192 + 16 * 32);
    }
    *(short8*)&sB[0][spx * BSTR + part * 8] = vst;
    __syncthreads();

#pragma unroll 1
    for (int s = 0; s < 36; s++) {
        const int p = s & 1;
        // prefetch next staging slab + next A (consumed after barrier)
        if (s < 35) {
            vst = *(const short8*)(stage_src + (size_t)(s + 1) * (N16K * 64));
            const ushort* wpn = wpbase + (size_t)(s + 1) * 2 * 8192;
#pragma unroll
            for (int kh = 0; kh < 2; kh++) {
                a0n[kh] = *(const short8*)(wpn + (size_t)kh * 8192);
                a1n[kh] = *(const short8*)(wpn + (size_t)kh * 8192 + 16 * 32);
            }
        }
        // B-frags from LDS + MFMA
#pragma unroll
        for (int kh = 0; kh < 2; kh++) {
#pragma unroll
            for (int nt = 0; nt < 4; nt++) {
                const short8 bfr = *(const short8*)&sB[p][(nt * 16 + l15) * BSTR +
                                                         kh * 32 + quad * 8];
                acc[0][nt] = __builtin_amdgcn_mfma_f32_16x16x32_bf16(a0c[kh], bfr, acc[0][nt], 0, 0, 0);
                acc[1][nt] = __builtin_amdgcn_mfma_f32_16x16x32_bf16(a1c[kh], bfr, acc[1][nt], 0, 0, 0);
            }
        }
        if (s < 35) {
            *(short8*)&sB[p ^ 1][spx * BSTR + part * 8] = vst;
            __syncthreads();
#pragma unroll
            for (int kh = 0; kh < 2; kh++) {
                a0c[kh] = a0n[kh];
                a1c[kh] = a1n[kh];
            }
        }
    }

    // ---- epilogue: bias, store, GN partial stats ----
    float gs[2], gq[2];
#pragma unroll
    for (int i = 0; i < 2; i++) {
        float sgn = 0.f, qq = 0.f;
        const int ob = wv * 32 + i * 16 + quad * 4;
#pragma unroll
        for (int reg = 0; reg < 4; reg++) {
            const int o = ob + reg;
            const float bv = bias[o];
            float* op = out + ((size_t)(b * 256 + o)) * HW + h * Ww + l15;
#pragma unroll
            for (int nt = 0; nt < 4; nt++) {
                const float v = acc[i][nt][reg] + bv;
                op[nt * 16] = v;
                sgn += v;
                qq += v * v;
            }
        }
        gs[i] = sgn; gq[i] = qq;
    }
#pragma unroll
    for (int off = 32; off; off >>= 1) {
        gs[0] += __shfl_xor(gs[0], off);
        gq[0] += __shfl_xor(gq[0], off);
        gs[1] += __shfl_xor(gs[1], off);
        gq[1] += __shfl_xor(gq[1], off);
    }
    if (lane == 0) {
#pragma unroll
        for (int i = 0; i < 2; i++) {
            const int g2 = wv * 2 + i;
            atomicAdd(&stats[((size_t)b * NG + g2) * 2],     gs[i]);
            atomicAdd(&stats[((size_t)b * NG + g2) * 2 + 1], gq[i]);
        }
    }
}

// ---------------------------------------------------------------------------
// Kernel 3: GN apply (mu/rsqrt from accumulated sums, in place)
// ---------------------------------------------------------------------------
__global__ void gn_apply_kernel(float* __restrict__ x, const float* __restrict__ stats,
                                const float* __restrict__ gamma,
                                const float* __restrict__ beta) {
    const int i = blockIdx.x * 256 + threadIdx.x;      // float4 idx, 1048576 total
    const int plane = i >> 10;                         // b*256 + o
    const int o = plane & 255;
    const int bg = plane >> 4;                         // b*16 + g
    const float s = stats[bg * 2], qv = stats[bg * 2 + 1];
    const float inv_n = 1.f / 65536.f;
    const float mu = s * inv_n;
    const float var = qv * inv_n - mu * mu;
    const float rs = rsqrtf(var + EPSV);
    const float ga = gamma[o] * rs;
    const float be = beta[o] - mu * ga;
    float4 v = ((float4*)x)[i];
    v.x = v.x * ga + be;
    v.y = v.y * ga + be;
    v.z = v.z * ga + be;
    v.w = v.w * ga + be;
    ((float4*)x)[i] = v;
}

// ---------------------------------------------------------------------------
extern "C" void kernel_launch(void* const* d_in, const int* in_sizes, int n_in,
                              void* d_out, int out_size, void* d_ws, size_t ws_size,
                              hipStream_t stream) {
    const float* input  = (const float*)d_in[0];
    const float* offset = (const float*)d_in[1];
    const float* maskp  = (const float*)d_in[2];
    const float* weight = (const float*)d_in[3];
    const float* bias   = (const float*)d_in[4];
    const float* gamma  = (const float*)d_in[5];
    const float* beta   = (const float*)d_in[6];
    float* out = (float*)d_out;

    // ws layout: in_t (16.78 MB) | wtb (1.18 MB) | col (75.5 MB) | stats
    float*  in_t  = (float*)d_ws;
    ushort* wtb   = (ushort*)((char*)d_ws + 16777216);
    ushort* col   = (ushort*)((char*)d_ws + 16777216 + 1179648);
    float*  stats = (float*)((char*)d_ws + 16777216 + 1179648 + 75497472);

    hipLaunchKernelGGL(prep_kernel, dim3(1024 + 2304), dim3(256), 0, stream,
                       input, in_t, weight, wtb, stats);
    hipLaunchKernelGGL(im2col_kernel, dim3(512), dim3(256), 0, stream,
                       in_t, offset, maskp, col);
    hipLaunchKernelGGL(gemm_kernel, dim3(256), dim3(512), 0, stream,
                       col, wtb, bias, out, stats);
    hipLaunchKernelGGL(gn_apply_kernel, dim3((Bsz * Cout * HW / 4) / 256), dim3(256), 0,
                       stream, out, stats, gamma, beta);
}